// Round 2
// baseline (259.349 us; speedup 1.0000x reference)
//
#include <hip/hip_runtime.h>

#define NB    1024
#define LQ    20
#define LD    200
#define E4    32      // EDIM/4
#define NK    21

// One block per (batch, pred). LDS ~29 KB -> 5 blocks/CU.
__global__ __launch_bounds__(256, 5) void knrm_main(
    const int* __restrict__ q1, const int* __restrict__ d1,
    const int* __restrict__ q2, const int* __restrict__ d2,
    const float* __restrict__ emb,
    const float* __restrict__ W1, const float* __restrict__ b1,
    const float* __restrict__ W2, const float* __restrict__ b2,
    const float* __restrict__ W3, const float* __restrict__ b3,
    float* __restrict__ logits)     // [2][NB] in workspace
{
    __shared__ float4 sQ4[LQ][E4];    // 10.25 KB
    __shared__ float  sQsq[LQ];
    __shared__ float  sQrn[LQ];
    __shared__ float  sM[LD][NK];     // 16.8 KB, stride 21 (odd -> conflict-free)
    __shared__ float  sPhi[LQ][NK];   // 1.68 KB
    __shared__ float  sX[NK];
    __shared__ float  sH1[10];
    __shared__ float  sH2[5];

    const int bp   = blockIdx.x;
    const int b    = bp & (NB - 1);
    const int pred = bp >> 10;
    const int t    = threadIdx.x;
    const int* __restrict__ qi = pred ? q2 : q1;
    const int* __restrict__ di = pred ? d2 : d1;
    const float4* emb4 = (const float4*)emb;

    // ---- init LDS accumulators ----
    if (t < LQ) sQsq[t] = 0.f;
    for (int p = t; p < LQ * NK; p += 256) ((float*)sPhi)[p] = 0.f;
    __syncthreads();

    // ---- Phase A: stage q rows into LDS + sumsq (8 threads/row, 160 active) ----
    if (t < 8 * LQ) {
        const int r = t >> 3, sub = t & 7;
        const int id = qi[b * LQ + r];
        const float4* src = emb4 + (size_t)id * E4;
        float s = 0.f;
        #pragma unroll
        for (int u = 0; u < 4; ++u) {
            float4 v = src[sub + 8 * u];
            sQ4[r][sub + 8 * u] = v;
            s += v.x * v.x + v.y * v.y + v.z * v.z + v.w * v.w;
        }
        atomicAdd(&sQsq[r], s);
    }
    __syncthreads();
    if (t < LQ) sQrn[t] = rsqrtf(sQsq[t] + 1e-6f);
    __syncthreads();

    // ---- Phase B: each thread owns 1 d-column ----
    if (t < LD) {
        const int j  = t;
        const int id = di[b * LD + j];
        const float4* pD = emb4 + (size_t)id * E4;

        float acc[LQ];
        #pragma unroll
        for (int i = 0; i < LQ; ++i) acc[i] = 0.f;
        float dsq = 0.f;

        for (int e4 = 0; e4 < E4; ++e4) {
            float4 a = pD[e4];
            dsq += a.x * a.x + a.y * a.y + a.z * a.z + a.w * a.w;
            #pragma unroll
            for (int i = 0; i < LQ; ++i) {
                float4 q = sQ4[i][e4];     // wave-uniform address -> broadcast
                acc[i] += q.x * a.x + q.y * a.y + q.z * a.z + q.w * a.w;
            }
        }
        const float rd = rsqrtf(dsq + 1e-6f);
        #pragma unroll
        for (int i = 0; i < LQ; ++i)
            sM[j][i] = acc[i] * sQrn[i] * rd;   // lane stride 21 floats: conflict-free
    }
    __syncthreads();

    // ---- Phase C: RBF kernels, sum over j (240 threads: 20 i x 12 slices) ----
    if (t < 240) {
        const int i = t % LQ, slice = t / LQ;   // 12 slices of 17 columns
        const int j0 = slice * 17;
        const int j1 = (j0 + 17 < LD) ? (j0 + 17) : LD;
        float S[NK];
        #pragma unroll
        for (int k = 0; k < NK; ++k) S[k] = 0.f;
        for (int j = j0; j < j1; ++j) {
            const float m = sM[j][i];
            #pragma unroll
            for (int k = 0; k < NK; ++k) {
                const float mu = (k < 20) ? (-0.95f + 0.1f * (float)k) : 1.0f;
                const float cc = (k < 20) ? -50.0f : -500000.0f;   // -1/(2*sig^2)
                const float d = m - mu;
                S[k] += __expf(d * d * cc);
            }
        }
        #pragma unroll
        for (int k = 0; k < NK; ++k) atomicAdd(&sPhi[i][k], S[k]);
    }
    __syncthreads();

    // ---- log1p + sum over i ----
    if (t < NK) {
        float s = 0.f;
        #pragma unroll
        for (int i = 0; i < LQ; ++i) s += __logf(1.0f + sPhi[i][t]);
        sX[t] = s;   // s >= 0, relu is a no-op
    }
    __syncthreads();

    // ---- MLP layer 1: 21 -> 10 ----
    if (t < 10) {
        float v = b1[t];
        #pragma unroll
        for (int k = 0; k < NK; ++k) v += W1[t * NK + k] * sX[k];
        sH1[t] = fmaxf(v, 0.f);
    }
    __syncthreads();

    // ---- MLP layer 2: 10 -> 5 ----
    if (t < 5) {
        float v = b2[t];
        #pragma unroll
        for (int k = 0; k < 10; ++k) v += W2[t * 10 + k] * sH1[k];
        sH2[t] = fmaxf(v, 0.f);
    }
    __syncthreads();

    // ---- MLP layer 3: 5 -> 1, write logit ----
    if (t == 0) {
        float v = b3[0];
        #pragma unroll
        for (int k = 0; k < 5; ++k) v += W3[k] * sH2[k];
        logits[pred * NB + b] = v;
    }
}

__global__ void knrm_combine(const float* __restrict__ logits, float* __restrict__ out)
{
    const int b = blockIdx.x * blockDim.x + threadIdx.x;
    if (b < NB) {
        // sigmoid(l1 - l2) = 1 / (1 + exp(l2 - l1))
        out[b] = 1.0f / (1.0f + __expf(logits[NB + b] - logits[b]));
    }
}

extern "C" void kernel_launch(void* const* d_in, const int* in_sizes, int n_in,
                              void* d_out, int out_size, void* d_ws, size_t ws_size,
                              hipStream_t stream) {
    float* logits = (float*)d_ws;   // 2*NB floats
    knrm_main<<<2 * NB, 256, 0, stream>>>(
        (const int*)d_in[0], (const int*)d_in[1],
        (const int*)d_in[2], (const int*)d_in[3],
        (const float*)d_in[4],
        (const float*)d_in[5], (const float*)d_in[6],
        (const float*)d_in[7], (const float*)d_in[8],
        (const float*)d_in[9], (const float*)d_in[10],
        logits);
    knrm_combine<<<(NB + 255) / 256, 256, 0, stream>>>(logits, (float*)d_out);
}

// Round 3
// 207.999 us; speedup vs baseline: 1.2469x; 1.2469x over previous
//
#include <hip/hip_runtime.h>

#define NB 1024
#define LQ 20
#define LD 200
#define E4 32      // 128 floats / 4
#define NK 21
#define NTILE 13   // ceil(208/16) N-tiles of 16 d-cols

typedef __attribute__((ext_vector_type(8))) short bf16x8;   // 8 bf16 = 4 VGPRs
typedef __attribute__((ext_vector_type(4))) float f32x4;

__device__ __forceinline__ short f2bf(float f, float& back) {
    unsigned u = __builtin_bit_cast(unsigned, f);
    unsigned r = (u + 0x7FFFu + ((u >> 16) & 1u)) >> 16;   // RNE
    back = __builtin_bit_cast(float, r << 16);
    return (short)r;
}

__device__ __forceinline__ bf16x8 make_frag(float4 f0, float4 f1, float& sq) {
    bf16x8 v; float bk;
    v[0] = f2bf(f0.x, bk); sq += bk * bk;
    v[1] = f2bf(f0.y, bk); sq += bk * bk;
    v[2] = f2bf(f0.z, bk); sq += bk * bk;
    v[3] = f2bf(f0.w, bk); sq += bk * bk;
    v[4] = f2bf(f1.x, bk); sq += bk * bk;
    v[5] = f2bf(f1.y, bk); sq += bk * bk;
    v[6] = f2bf(f1.z, bk); sq += bk * bk;
    v[7] = f2bf(f1.w, bk); sq += bk * bk;
    return v;
}

__device__ __forceinline__ float fast_exp2(float x) {
#if __has_builtin(__builtin_amdgcn_exp2f)
    return __builtin_amdgcn_exp2f(x);
#else
    return __expf(x * 0.69314718056f);
#endif
}

// One block per (batch, pred).
__global__ __launch_bounds__(256, 4) void knrm_main(
    const int* __restrict__ q1, const int* __restrict__ d1,
    const int* __restrict__ q2, const int* __restrict__ d2,
    const float* __restrict__ emb,
    const float* __restrict__ W1, const float* __restrict__ b1,
    const float* __restrict__ W2, const float* __restrict__ b2,
    const float* __restrict__ W3, const float* __restrict__ b3,
    float* __restrict__ logits)     // [2][NB] in workspace
{
    __shared__ float sM[LD][20];     // 16.0 KB, j-major; [j][i]
    __shared__ float sPhi[LQ][NK];   // 1.68 KB
    __shared__ float sX[NK];
    __shared__ float sH1[10];
    __shared__ float sH2[5];

    const int bp   = blockIdx.x;
    const int b    = bp & (NB - 1);
    const int pred = bp >> 10;
    const int t    = threadIdx.x;
    const int lane = t & 63, wave = t >> 6;
    const int c    = lane & 15, quad = lane >> 4;
    const int* __restrict__ qi = pred ? q2 : q1;
    const int* __restrict__ di = pred ? d2 : d1;
    const float4* emb4 = (const float4*)emb;

    for (int p = t; p < LQ * NK; p += 256) ((float*)sPhi)[p] = 0.f;

    // ---- Load A (Q) fragments: 2 M-tiles x 4 K-steps; norms from bf16 values ----
    bf16x8 aF[2][4];
    float  rqv[2][4];
    #pragma unroll
    for (int Mt = 0; Mt < 2; ++Mt) {
        const int row = Mt * 16 + c;
        const int id  = qi[b * LQ + (row < LQ ? row : LQ - 1)];
        const float4* qb = emb4 + (size_t)id * E4;
        float qs = 0.f;
        #pragma unroll
        for (int ks = 0; ks < 4; ++ks) {
            float4 f0 = qb[ks * 8 + quad * 2];
            float4 f1 = qb[ks * 8 + quad * 2 + 1];
            aF[Mt][ks] = make_frag(f0, f1, qs);
        }
        if (row >= LQ) {             // zero the padded rows 20..31
            #pragma unroll
            for (int ks = 0; ks < 4; ++ks) aF[Mt][ks] = (bf16x8)0;
            qs = 0.f;
        }
        qs += __shfl_xor(qs, 16);    // butterfly across quads (k-chunks)
        qs += __shfl_xor(qs, 32);
        const float rq = rsqrtf(qs + 1e-6f);
        #pragma unroll
        for (int r = 0; r < 4; ++r)
            rqv[Mt][r] = __shfl(rq, quad * 4 + r);   // rq for C-row quad*4+r
    }

    // ---- Phase B: N-tiles of 16 d-cols per wave; MFMA; scale; store M to LDS ----
    for (int tile = wave; tile < NTILE; tile += 4) {
        const int j  = tile * 16 + c;
        const int id = di[b * LD + (j < LD ? j : LD - 1)];
        const float4* db = emb4 + (size_t)id * E4;
        bf16x8 bF[4];
        float dsq = 0.f;
        #pragma unroll
        for (int ks = 0; ks < 4; ++ks) {
            float4 f0 = db[ks * 8 + quad * 2];
            float4 f1 = db[ks * 8 + quad * 2 + 1];
            bF[ks] = make_frag(f0, f1, dsq);
        }
        dsq += __shfl_xor(dsq, 16);
        dsq += __shfl_xor(dsq, 32);
        const float rd = rsqrtf(dsq + 1e-6f);

        f32x4 acc0 = {0.f, 0.f, 0.f, 0.f};
        f32x4 acc1 = {0.f, 0.f, 0.f, 0.f};
        #pragma unroll
        for (int ks = 0; ks < 4; ++ks) {
            acc0 = __builtin_amdgcn_mfma_f32_16x16x32_bf16(aF[0][ks], bF[ks], acc0, 0, 0, 0);
            acc1 = __builtin_amdgcn_mfma_f32_16x16x32_bf16(aF[1][ks], bF[ks], acc1, 0, 0, 0);
        }
        if (j < LD) {
            // C layout: col = lane&15 (=j), row = quad*4 + reg
            float4 v0;
            v0.x = acc0[0] * rqv[0][0] * rd;
            v0.y = acc0[1] * rqv[0][1] * rd;
            v0.z = acc0[2] * rqv[0][2] * rd;
            v0.w = acc0[3] * rqv[0][3] * rd;
            *(float4*)&sM[j][quad * 4] = v0;          // rows quad*4..+3
            if (quad == 0) {                          // rows 16..19 from Mt1
                float4 v1;
                v1.x = acc1[0] * rqv[1][0] * rd;
                v1.y = acc1[1] * rqv[1][1] * rd;
                v1.z = acc1[2] * rqv[1][2] * rd;
                v1.w = acc1[3] * rqv[1][3] * rd;
                *(float4*)&sM[j][16] = v1;
            }
        }
    }
    __syncthreads();

    // ---- Phase C: RBF kernels via exp2 identity ----
    // phi_k = Ck * 2^(B2*m*mu_k + C2*m^2),  Ck = e^{-50 mu_k^2}
    if (t < 240) {
        const int i = t / 12, slice = t % 12;
        const int j0 = slice * 17;
        const int j1 = (j0 + 17 < LD) ? (j0 + 17) : LD;
        const float C2  = -72.13475204f;     // -50*log2(e)
        const float B2  = 144.26950408f;     // 100*log2(e)
        const float C2E = -721347.5204f;     // -5e5*log2(e)
        const float CK[20] = {
            2.52616e-20f, 2.04697e-16f, 6.10193e-13f, 6.69158e-10f, 2.69958e-7f,
            4.00653e-5f,  2.18749e-3f,  4.39369e-2f,  3.24652e-1f,  8.82497e-1f,
            8.82497e-1f,  3.24652e-1f,  4.39369e-2f,  2.18749e-3f,  4.00653e-5f,
            2.69958e-7f,  6.69158e-10f, 6.10193e-13f, 2.04697e-16f, 2.52616e-20f };
        float S[NK];
        #pragma unroll
        for (int k = 0; k < NK; ++k) S[k] = 0.f;
        for (int j = j0; j < j1; ++j) {
            const float m  = sM[j][i];
            const float a  = C2 * m * m;
            const float bb = B2 * m;
            #pragma unroll
            for (int k = 0; k < 20; ++k) {
                const float mu = 0.1f * (float)k - 0.95f;
                S[k] = fmaf(CK[k], fast_exp2(fmaf(bb, mu, a)), S[k]);
            }
            const float d = m - 1.0f;
            S[20] += fast_exp2(d * d * C2E);   // exact kernel, sigma=0.001
        }
        #pragma unroll
        for (int k = 0; k < NK; ++k) atomicAdd(&sPhi[i][k], S[k]);
    }
    __syncthreads();

    // ---- log1p + sum over i ----
    if (t < NK) {
        float s = 0.f;
        #pragma unroll
        for (int i = 0; i < LQ; ++i) s += __logf(1.0f + sPhi[i][t]);
        sX[t] = s;   // s >= 0, relu no-op
    }
    __syncthreads();

    if (t < 10) {
        float v = b1[t];
        #pragma unroll
        for (int k = 0; k < NK; ++k) v += W1[t * NK + k] * sX[k];
        sH1[t] = fmaxf(v, 0.f);
    }
    __syncthreads();

    if (t < 5) {
        float v = b2[t];
        #pragma unroll
        for (int k = 0; k < 10; ++k) v += W2[t * 10 + k] * sH1[k];
        sH2[t] = fmaxf(v, 0.f);
    }
    __syncthreads();

    if (t == 0) {
        float v = b3[0];
        #pragma unroll
        for (int k = 0; k < 5; ++k) v += W3[k] * sH2[k];
        logits[pred * NB + b] = v;
    }
}

__global__ void knrm_combine(const float* __restrict__ logits, float* __restrict__ out)
{
    const int b = blockIdx.x * blockDim.x + threadIdx.x;
    if (b < NB) {
        out[b] = 1.0f / (1.0f + __expf(logits[NB + b] - logits[b]));
    }
}

extern "C" void kernel_launch(void* const* d_in, const int* in_sizes, int n_in,
                              void* d_out, int out_size, void* d_ws, size_t ws_size,
                              hipStream_t stream) {
    float* logits = (float*)d_ws;   // 2*NB floats
    knrm_main<<<2 * NB, 256, 0, stream>>>(
        (const int*)d_in[0], (const int*)d_in[1],
        (const int*)d_in[2], (const int*)d_in[3],
        (const float*)d_in[4],
        (const float*)d_in[5], (const float*)d_in[6],
        (const float*)d_in[7], (const float*)d_in[8],
        (const float*)d_in[9], (const float*)d_in[10],
        logits);
    knrm_combine<<<(NB + 255) / 256, 256, 0, stream>>>(logits, (float*)d_out);
}